// Round 10
// baseline (348.670 us; speedup 1.0000x reference)
//
#include <hip/hip_runtime.h>
#include <hip/hip_bf16.h>

typedef __attribute__((ext_vector_type(8))) short short8;
typedef __attribute__((ext_vector_type(4))) float floatx4;

#define NB   196     // dst-range buckets: bkt = dst >> 8  (50000/256 -> 196)
#define NBLK 256     // edge-chunk blocks for binning

__device__ __forceinline__ float bf_lo(unsigned int u) { return __uint_as_float(u << 16); }
__device__ __forceinline__ float bf_hi(unsigned int u) { return __uint_as_float(u & 0xffff0000u); }

__device__ __forceinline__ unsigned short f2bf_rne(float f) {
    unsigned u = __float_as_uint(f);
    unsigned rb = (u >> 16) & 1u;
    u += 0x7fffu + rb;
    return (unsigned short)(u >> 16);
}
__device__ __forceinline__ unsigned int pack_bf2(float x, float y) {
    return (unsigned int)f2bf_rne(x) | ((unsigned int)f2bf_rne(y) << 16);
}

__device__ __forceinline__ void acc4(unsigned long long v, float& f0, float& f1, float& f2, float& f3) {
    unsigned ua = (unsigned)v, ub = (unsigned)(v >> 32);
    f0 += bf_lo(ua); f1 += bf_hi(ua); f2 += bf_lo(ub); f3 += bf_hi(ub);
}

// ---------------- prep: binA bucket-histogram (blocks [0,NBLK)) + convert/pack (rest) ----------------

__global__ __launch_bounds__(256) void prep_kernel(const int* __restrict__ dst,
                                                   int* __restrict__ blockcnt,   // [NB*NBLK]
                                                   int E,
                                                   const float* __restrict__ x,
                                                   const float* __restrict__ W1,
                                                   const float* __restrict__ W2,
                                                   const float* __restrict__ W3,
                                                   const float* __restrict__ Wp, const float* __restrict__ bp,
                                                   const float* __restrict__ Wc, const float* __restrict__ bc,
                                                   unsigned int* __restrict__ xb,
                                                   unsigned int* __restrict__ W1b,
                                                   unsigned int* __restrict__ W2b,
                                                   unsigned int* __restrict__ W3b,
                                                   unsigned int* __restrict__ Whb,
                                                   float* __restrict__ hbias,
                                                   int nx) {
    if ((int)blockIdx.x < NBLK) {
        __shared__ int hist[NB];
        for (int i = threadIdx.x; i < NB; i += 256) hist[i] = 0;
        __syncthreads();
        const int chunk = (E + NBLK - 1) / NBLK;
        const int lo = blockIdx.x * chunk;
        const int hi = min(lo + chunk, E);
        for (int e = lo + threadIdx.x; e < hi; e += 256)
            atomicAdd(&hist[dst[e] >> 8], 1);          // LDS atomic, block-local
        __syncthreads();
        for (int i = threadIdx.x; i < NB; i += 256)
            blockcnt[i * NBLK + blockIdx.x] = hist[i]; // bucket-major layout for scan
        return;
    }
    int i = (blockIdx.x - NBLK) * 256 + threadIdx.x;
    const int T0 = nx;            // x pairs
    const int T1 = T0 + 4096;     // W1 128x64
    const int T2 = T1 + 8192;     // W2 128x128
    const int T3 = T2 + 4096;     // W3 64x128
    const int T4 = T3 + 2560;     // Whb 80x64
    const int T5 = T4 + 80;       // hbias
    if (i < T0) {
        float2 f = ((const float2*)x)[i];
        xb[i] = pack_bf2(f.x, f.y);
    } else if (i < T1) {
        float2 f = ((const float2*)W1)[i - T0];
        W1b[i - T0] = pack_bf2(f.x, f.y);
    } else if (i < T2) {
        float2 f = ((const float2*)W2)[i - T1];
        W2b[i - T1] = pack_bf2(f.x, f.y);
    } else if (i < T3) {
        float2 f = ((const float2*)W3)[i - T2];
        W3b[i - T2] = pack_bf2(f.x, f.y);
    } else if (i < T4) {
        int j = i - T3;
        int r = j >> 5, c = (j & 31) * 2;
        float v0 = 0.f, v1 = 0.f;
        if (r < 64)      { v0 = Wp[r * 64 + c]; v1 = Wp[r * 64 + c + 1]; }
        else if (r < 74) { v0 = Wc[(r - 64) * 64 + c]; v1 = Wc[(r - 64) * 64 + c + 1]; }
        Whb[j] = pack_bf2(v0, v1);
    } else if (i < T5) {
        int j = i - T4;
        float v = 0.f;
        if (j < 64)      v = bp[j];
        else if (j < 74) v = bc[j - 64];
        hbias[j] = v;
    }
}

// ---------------- scan over blockcnt (items = NB*NBLK) -> exact exclusive base ----------------

__global__ __launch_bounds__(256) void partial_sum_kernel(const int* __restrict__ v,
                                                          int* __restrict__ partial, int n) {
    __shared__ int s[256];
    int t = threadIdx.x;
    int i = blockIdx.x * 256 + t;
    s[t] = (i < n) ? v[i] : 0;
    __syncthreads();
    for (int off = 128; off > 0; off >>= 1) {
        if (t < off) s[t] += s[t + off];
        __syncthreads();
    }
    if (t == 0) partial[blockIdx.x] = s[0];
}

__global__ __launch_bounds__(256) void local_scan_kernel(const int* __restrict__ v,
                                                         const int* __restrict__ partial,
                                                         int* __restrict__ base,
                                                         int nblocks, int n) {
    __shared__ int sp[256];
    __shared__ int s[256];
    int t = threadIdx.x;
    sp[t] = (t < nblocks) ? partial[t] : 0;
    __syncthreads();
    for (int off = 1; off < 256; off <<= 1) {
        int u = (t >= off) ? sp[t - off] : 0;
        __syncthreads();
        sp[t] += u;
        __syncthreads();
    }
    const int blockbase = (blockIdx.x == 0) ? 0 : sp[blockIdx.x - 1];
    if (blockIdx.x == 0 && t == 0) base[n] = sp[nblocks - 1];   // total = E

    int i = blockIdx.x * 256 + t;
    int w = (i < n) ? v[i] : 0;
    s[t] = w;
    __syncthreads();
    for (int off = 1; off < 256; off <<= 1) {
        int u = (t >= off) ? s[t - off] : 0;
        __syncthreads();
        s[t] += u;
        __syncthreads();
    }
    if (i < n) base[i] = blockbase + s[t] - w;   // exclusive prefix
}

// ---------------- binC: rank within (block,bucket) in LDS, write packed pairs ----------------

__global__ __launch_bounds__(256) void binC_kernel(const int* __restrict__ src,
                                                   const int* __restrict__ dst,
                                                   const int* __restrict__ base,
                                                   unsigned int* __restrict__ pairs, int E) {
    __shared__ int bbase[NB];
    __shared__ int cur[NB];
    for (int i = threadIdx.x; i < NB; i += 256) {
        bbase[i] = base[i * NBLK + blockIdx.x];
        cur[i] = 0;
    }
    __syncthreads();
    const int chunk = (E + NBLK - 1) / NBLK;
    const int lo = blockIdx.x * chunk;
    const int hi = min(lo + chunk, E);
    for (int e = lo + threadIdx.x; e < hi; e += 256) {
        int d = dst[e];
        int b = d >> 8;
        int r = atomicAdd(&cur[b], 1);                 // LDS atomic, block-local
        pairs[bbase[b] + r] = ((unsigned)d << 16) | (unsigned)src[e];
    }
}

// ---------------- bucketD: per-node count+scan in LDS -> offsets + csr scatter ----------------

__global__ __launch_bounds__(256) void bucketD_kernel(const unsigned int* __restrict__ pairs,
                                                      const int* __restrict__ base,
                                                      int* __restrict__ offsets,
                                                      unsigned short* __restrict__ csr_src,
                                                      int E, int n) {
    __shared__ int cnt[256];
    __shared__ int loc[256];
    const int b = blockIdx.x;
    const int start = base[b * NBLK];
    const int end   = base[(b + 1) * NBLK];   // b=NB-1 reads base[NB*NBLK] = E
    const int t = threadIdx.x;

    cnt[t] = 0;
    __syncthreads();
    for (int i = start + t; i < end; i += 256)
        atomicAdd(&cnt[(pairs[i] >> 16) & 255], 1);    // local node index = dst & 255
    __syncthreads();

    loc[t] = cnt[t];
    __syncthreads();
    for (int off = 1; off < 256; off <<= 1) {
        int u = (t >= off) ? loc[t - off] : 0;
        __syncthreads();
        loc[t] += u;
        __syncthreads();
    }
    const int excl = (t == 0) ? 0 : loc[t - 1];

    const int d = (b << 8) + t;
    if (d < n) offsets[d] = start + excl;
    if (b == 0 && t == 0) offsets[n] = E;

    __syncthreads();
    cnt[t] = excl;            // cursor = local exclusive prefix
    __syncthreads();
    for (int i = start + t; i < end; i += 256) {
        unsigned pr = pairs[i];
        int j = (pr >> 16) & 255;
        int p = atomicAdd(&cnt[j], 1);                 // LDS atomic, block-local
        csr_src[start + p] = (unsigned short)(pr & 0xffffu);
    }
}

// ---------------- XCD-sliced aggregation ----------------
// slice = blockIdx % NSLICE; with HW round-robin blockIdx%8 -> XCD, XCD i always
// touches only column-slice (i % NSLICE) = 64B/row = 3.2MB -> fits its 4MB L2,
// eliminating the 8x table thrash (FETCH 79MB -> ~26MB predicted).
// 256 thr = 4 waves x 4 nodes. Per node: 8 edge-groups x 8 u64-cols; 8 gather
// instrs (512B each) in flight; per-column edge accumulation order is the node's
// csr order (numerics per element identical to the fused version).

template <int F_IN, int NSLICE>
__global__ __launch_bounds__(256) void agg_slice_kernel(
        const unsigned long long* __restrict__ xt,   // F_IN/4 u64 per row
        const int* __restrict__ offsets,
        const unsigned short* __restrict__ csr_src,
        unsigned long long* __restrict__ hb,         // same layout as xt
        int n) {
    constexpr int XSTR = F_IN / 4;
    const int lane = threadIdx.x & 63;
    const int wv   = threadIdx.x >> 6;          // 0..3
    const int s    = blockIdx.x % NSLICE;       // slice, aligned to XCD
    const int nb   = blockIdx.x / NSLICE;       // node block (16 nodes)
    const int g    = lane >> 3;                 // edge group 0..7
    const int c    = lane & 7;                  // u64 col within slice
    const int col  = s * 8 + c;                 // u64 col within row

#pragma unroll 1
    for (int i = 0; i < 4; ++i) {
        const int node = nb * 16 + wv * 4 + i;   // wave-uniform
        if (node >= n) continue;
        const int ns = offsets[node];
        const int ne = offsets[node + 1];
        const int cnt = ne - ns;
        unsigned long long sv = xt[(size_t)node * XSTR + col];

        float s0 = 0.f, s1 = 0.f, s2 = 0.f, s3 = 0.f;
        for (int base = 0; base < cnt; base += 64) {
            int ii = ns + base + lane; if (ii >= ne) ii = ne - 1;
            int idx = csr_src[ii];
            int m = cnt - base; if (m > 64) m = 64;
            unsigned long long v[8];
#pragma unroll
            for (int q = 0; q < 8; ++q) {
                int nb2 = __shfl(idx, q * 8 + g, 64);   // all lanes execute
                if (q * 8 + g < m) v[q] = xt[(size_t)nb2 * XSTR + col];
            }
#pragma unroll
            for (int q = 0; q < 8; ++q)
                if (q * 8 + g < m) acc4(v[q], s0, s1, s2, s3);
        }
        // reduce over the 8 edge groups (lane bits 3,4,5)
        s0 += __shfl(s0, lane ^ 8, 64);  s1 += __shfl(s1, lane ^ 8, 64);
        s2 += __shfl(s2, lane ^ 8, 64);  s3 += __shfl(s3, lane ^ 8, 64);
        s0 += __shfl(s0, lane ^ 16, 64); s1 += __shfl(s1, lane ^ 16, 64);
        s2 += __shfl(s2, lane ^ 16, 64); s3 += __shfl(s3, lane ^ 16, 64);
        s0 += __shfl(s0, lane ^ 32, 64); s1 += __shfl(s1, lane ^ 32, 64);
        s2 += __shfl(s2, lane ^ 32, 64); s3 += __shfl(s3, lane ^ 32, 64);

        if (g == 0) {
            float inv = 1.0f / fmaxf((float)cnt, 1.0f);
            unsigned ua = (unsigned)sv, ub = (unsigned)(sv >> 32);
            unsigned o0 = pack_bf2(s0 * inv + bf_lo(ua), s1 * inv + bf_hi(ua));
            unsigned o1 = pack_bf2(s2 * inv + bf_lo(ub), s3 * inv + bf_hi(ub));
            hb[(size_t)node * XSTR + col] = ((unsigned long long)o1 << 32) | o0;
        }
    }
}

// ---------------- MFMA GEMM: Y = act(H @ W^T + b), bf16 in, fp32 accum ----------------
// MODE 0: bf16 out + relu.  MODE 3: layer3+heads (relu, fp32 emb, heads via LDS Ytile).
// (round-0 proven kernel, verbatim)

template <int F_IN, int F_OUT, int MODE>
__global__ __launch_bounds__(256) void mfma_gemm_kernel(const unsigned short* __restrict__ Hb,
                                                        const unsigned short* __restrict__ Wb,
                                                        const float* __restrict__ bias,
                                                        unsigned short* __restrict__ Yb,
                                                        float* __restrict__ Yf,
                                                        float* __restrict__ nev,
                                                        float* __restrict__ cls,
                                                        const unsigned short* __restrict__ Whb,
                                                        const float* __restrict__ hbias,
                                                        int n) {
    constexpr int KC = F_IN / 32;
    constexpr int NJ = F_OUT / 16;
    __shared__ unsigned short Ytile[(MODE == 3) ? 64 * 72 : 1];

    const int lane = threadIdx.x & 63;
    const int wv   = threadIdx.x >> 6;
    const int quad = lane >> 4;
    const int r16  = lane & 15;
    const int m0   = blockIdx.x * 64 + wv * 16;

    short8 a[KC];
    const int am = m0 + r16;
    if (am < n) {
#pragma unroll
        for (int c = 0; c < KC; ++c)
            a[c] = *(const short8*)&Hb[(size_t)am * F_IN + 32 * c + quad * 8];
    } else {
#pragma unroll
        for (int c = 0; c < KC; ++c)
#pragma unroll
            for (int i = 0; i < 8; ++i) a[c][i] = 0;
    }

    floatx4 acc[NJ];
#pragma unroll
    for (int j = 0; j < NJ; ++j)
#pragma unroll
        for (int r = 0; r < 4; ++r) acc[j][r] = 0.f;

#pragma unroll
    for (int j = 0; j < NJ; ++j) {
#pragma unroll
        for (int c = 0; c < KC; ++c) {
            short8 b = *(const short8*)&Wb[(size_t)(16 * j + r16) * F_IN + 32 * c + quad * 8];
            acc[j] = __builtin_amdgcn_mfma_f32_16x16x32_bf16(a[c], b, acc[j], 0, 0, 0);
        }
    }

#pragma unroll
    for (int r = 0; r < 4; ++r) {
        const int mm = m0 + quad * 4 + r;
        const int lrow = wv * 16 + quad * 4 + r;
#pragma unroll
        for (int j = 0; j < NJ; ++j) {
            const int o = 16 * j + r16;
            if (mm < n) {
                float v = fmaxf(acc[j][r] + bias[o], 0.f);
                if (MODE == 0) {
                    Yb[(size_t)mm * F_OUT + o] = f2bf_rne(v);
                } else {
                    Yf[(size_t)mm * 64 + o] = v;
                    Ytile[lrow * 72 + o] = f2bf_rne(v);
                }
            } else if (MODE == 3) {
                Ytile[lrow * 72 + o] = 0;
            }
        }
    }

    if (MODE == 3) {
        __syncthreads();

        short8 a2[2];
#pragma unroll
        for (int c = 0; c < 2; ++c)
            a2[c] = *(const short8*)&Ytile[(wv * 16 + r16) * 72 + 32 * c + quad * 8];

        floatx4 acc2[5];
#pragma unroll
        for (int j = 0; j < 5; ++j)
#pragma unroll
            for (int r = 0; r < 4; ++r) acc2[j][r] = 0.f;

#pragma unroll
        for (int j = 0; j < 5; ++j)
#pragma unroll
            for (int c = 0; c < 2; ++c) {
                short8 b = *(const short8*)&Whb[(size_t)(16 * j + r16) * 64 + 32 * c + quad * 8];
                acc2[j] = __builtin_amdgcn_mfma_f32_16x16x32_bf16(a2[c], b, acc2[j], 0, 0, 0);
            }

#pragma unroll
        for (int r = 0; r < 4; ++r) {
            const int mm = m0 + quad * 4 + r;
            if (mm >= n) continue;
#pragma unroll
            for (int j = 0; j < 5; ++j) {
                const int o = 16 * j + r16;
                float v = acc2[j][r] + hbias[o];
                if (o < 64)      nev[(size_t)mm * 64 + o] = v;
                else if (o < 74) cls[(size_t)mm * 10 + (o - 64)] = v;
            }
        }
    }
}

// ---------------- launch ----------------

extern "C" void kernel_launch(void* const* d_in, const int* in_sizes, int n_in,
                              void* d_out, int out_size, void* d_ws, size_t ws_size,
                              hipStream_t stream) {
    const float* x  = (const float*)d_in[0];
    const int*   ei = (const int*)d_in[1];
    const float* W1 = (const float*)d_in[2];
    const float* b1 = (const float*)d_in[3];
    const float* W2 = (const float*)d_in[4];
    const float* b2 = (const float*)d_in[5];
    const float* W3 = (const float*)d_in[6];
    const float* b3 = (const float*)d_in[7];
    const float* Wp = (const float*)d_in[8];
    const float* bp = (const float*)d_in[9];
    const float* Wc = (const float*)d_in[10];
    const float* bc = (const float*)d_in[11];

    const int n = in_sizes[0] / 64;   // 50000
    const int E = in_sizes[1] / 2;    // 800000
    const int* src = ei;
    const int* dst = ei + E;

    const int items = NB * NBLK;                 // 50176
    const int nScan = (items + 255) / 256;       // 196

    // workspace layout (no memset, no global atomics)
    int* blockcnt = (int*)d_ws;                    // items
    int* base     = blockcnt + items;              // items + 1
    int* partial  = base + items + 1;              // 256
    int* offsets  = partial + 256;                 // n + 1
    unsigned int*   pairs   = (unsigned int*)(offsets + n + 1);   // E u32 (dst<<16|src)
    unsigned short* csr_src = (unsigned short*)(pairs + E);       // E u16
    uintptr_t p = (uintptr_t)(csr_src + E);
    p = (p + 255) & ~(uintptr_t)255;
    unsigned int* Ab  = (unsigned int*)p;          // n*64 (agg out, up to n x 128 bf16)
    unsigned int* Hb  = Ab + (size_t)n * 64;       // n*64
    unsigned int* Yb  = Hb + (size_t)n * 64;       // n*64
    unsigned int* xb  = Yb + (size_t)n * 64;       // n*32 (n x 64 bf16)
    unsigned int* W1b = xb + (size_t)n * 32;       // 4096 uints
    unsigned int* W2b = W1b + 4096;                // 8192
    unsigned int* W3b = W2b + 8192;                // 4096
    unsigned int* Whb = W3b + 4096;                // 2560
    float* hbias = (float*)(Whb + 2560);           // 80

    float* out_emb = (float*)d_out;
    float* out_nev = out_emb + (size_t)n * 64;
    float* out_cls = out_nev + (size_t)n * 64;

    const int convTotal = n * 32 + 4096 + 8192 + 4096 + 2560 + 80;
    const int convBlocks = (convTotal + 255) / 256;
    prep_kernel<<<NBLK + convBlocks, 256, 0, stream>>>(
        dst, blockcnt, E,
        x, W1, W2, W3, Wp, bp, Wc, bc, xb, W1b, W2b, W3b, Whb, hbias, n * 32);

    partial_sum_kernel<<<nScan, 256, 0, stream>>>(blockcnt, partial, items);
    local_scan_kernel<<<nScan, 256, 0, stream>>>(blockcnt, partial, base, nScan, items);

    binC_kernel<<<NBLK, 256, 0, stream>>>(src, dst, base, pairs, E);
    bucketD_kernel<<<NB, 256, 0, stream>>>(pairs, base, offsets, csr_src, E, n);

    const int nNB = (n + 15) / 16;     // 3125 node blocks
    const int gMf = (n + 63) / 64;     // 782 GEMM blocks

    // layer 1: sliced agg(xb, F=64) -> Ab; GEMM 64->128 -> Hb
    agg_slice_kernel<64, 2><<<nNB * 2, 256, 0, stream>>>(
        (const unsigned long long*)xb, offsets, csr_src, (unsigned long long*)Ab, n);
    mfma_gemm_kernel<64, 128, 0><<<gMf, 256, 0, stream>>>(
        (const unsigned short*)Ab, (const unsigned short*)W1b, b1,
        (unsigned short*)Hb, nullptr, nullptr, nullptr, nullptr, nullptr, n);

    // layer 2: sliced agg(Hb, F=128) -> Ab; GEMM 128->128 -> Yb
    agg_slice_kernel<128, 4><<<nNB * 4, 256, 0, stream>>>(
        (const unsigned long long*)Hb, offsets, csr_src, (unsigned long long*)Ab, n);
    mfma_gemm_kernel<128, 128, 0><<<gMf, 256, 0, stream>>>(
        (const unsigned short*)Ab, (const unsigned short*)W2b, b2,
        (unsigned short*)Yb, nullptr, nullptr, nullptr, nullptr, nullptr, n);

    // layer 3: sliced agg(Yb, F=128) -> Ab; GEMM 128->64 + heads -> outputs
    agg_slice_kernel<128, 4><<<nNB * 4, 256, 0, stream>>>(
        (const unsigned long long*)Yb, offsets, csr_src, (unsigned long long*)Ab, n);
    mfma_gemm_kernel<128, 64, 3><<<gMf, 256, 0, stream>>>(
        (const unsigned short*)Ab, (const unsigned short*)W3b, b3,
        nullptr, out_emb, out_nev, out_cls, (const unsigned short*)Whb, hbias, n);
}